// Round 14
// baseline (123.143 us; speedup 1.0000x reference)
//
#include <hip/hip_runtime.h>
#include <stdint.h>

// Problem constants (fixed by reference)
#define BATCH 16
#define CH    512
#define HW    2304           // 48*48
#define BM    128
#define BN    128

typedef _Float16 half8  __attribute__((ext_vector_type(8)));
typedef float    f32x16 __attribute__((ext_vector_type(16)));

#define MFMA16 __builtin_amdgcn_mfma_f32_32x32x16_f16

// Rescore margin: |E - E_hi| <= Sum|q||k| * 2^-10 ~= 1.5 (worst-case, Sum
// concentrates at ~1467); pairwise <= 3.1 < 3.5 -> true argmax provably in
// the candidate set. Proven absmax 0.0 in R13 with identical f16 arithmetic.
#define DELTA 3.5f

#define N_ELEM       ((size_t)BATCH * CH * HW)    // 18.87M per input
#define ENERGY_ELEMS ((size_t)BATCH * CH * CH)    // 4.19M f32 = 16.78 MB
#define WS_FAST16    (ENERGY_ELEMS * 4 + 2 * N_ELEM * 2)   // 92.3 MB

// float -> order-preserving uint32
__device__ __forceinline__ uint32_t f32_sortable(float f) {
    uint32_t u = __float_as_uint(f);
    return (u & 0x80000000u) ? ~u : (u | 0x80000000u);
}

// ===================== cvt: f32 -> f16, both inputs ========================
__global__ __launch_bounds__(256)
void cvt_f16_kernel(const float* __restrict__ rgb, const float* __restrict__ depth,
                    _Float16* __restrict__ rgb16, _Float16* __restrict__ depth16)
{
    const size_t stride = (size_t)gridDim.x * 256;
    for (size_t i = (size_t)blockIdx.x * 256 + threadIdx.x; i < N_ELEM / 8; i += stride) {
        float4 a0 = ((const float4*)rgb)[2 * i], a1 = ((const float4*)rgb)[2 * i + 1];
        half8 h;
        h[0] = (_Float16)a0.x; h[1] = (_Float16)a0.y;
        h[2] = (_Float16)a0.z; h[3] = (_Float16)a0.w;
        h[4] = (_Float16)a1.x; h[5] = (_Float16)a1.y;
        h[6] = (_Float16)a1.z; h[7] = (_Float16)a1.w;
        ((half8*)rgb16)[i] = h;
        float4 b0 = ((const float4*)depth)[2 * i], b1 = ((const float4*)depth)[2 * i + 1];
        half8 g;
        g[0] = (_Float16)b0.x; g[1] = (_Float16)b0.y;
        g[2] = (_Float16)b0.z; g[3] = (_Float16)b0.w;
        g[4] = (_Float16)b1.x; g[5] = (_Float16)b1.y;
        g[6] = (_Float16)b1.z; g[7] = (_Float16)b1.w;
        ((half8*)depth16)[i] = g;
    }
}

// ================ screen16: f16 DMA GEMM -> energy matrix ==================
// m97-structure port: 128x128 tile, BK=64 f16, 512 thr / 8 waves of 64x32,
// global_load_lds (16B) staging, counted vmcnt(4), 2 raw barriers/step.
// LDS[r][s] = G[r][s ^ ((r>>1)&7)] via pre-swizzled per-lane SOURCE address
// (G21: DMA dest must stay linear); reads use the same XOR -> 2/bank floor.

#define BK16    64
#define NKT16   (HW / BK16)      // 36
#define A16_OFF 0
#define B16_OFF 16384            // each 128 rows x 128 B
#define BUF16_SZ 32768           // 32 KB ; x2 = 64 KB

__device__ __forceinline__ void dma16(const _Float16* g, char* l) {
    __builtin_amdgcn_global_load_lds(
        (const __attribute__((address_space(1))) void*)g,
        (__attribute__((address_space(3))) void*)l, 16, 0, 0);
}

__device__ __forceinline__ half8 rd16(const char* base, int r, int s0) {
    return *(const half8*)(base + r * 128 + ((s0 ^ ((r >> 1) & 7)) << 4));
}

// One K64 step for a 64x32 wave tile: 12 ds_read_b128 -> 8 MFMA.
__device__ __forceinline__ void compute16(const char* buf, int rA0, int rB, int hf,
                                          f32x16& acc0, f32x16& acc1) {
    __builtin_amdgcn_s_setprio(1);
    #pragma unroll
    for (int kc = 0; kc < 4; ++kc) {
        const int s0 = 2 * kc + hf;
        half8 a0 = rd16(buf + A16_OFF, rA0,      s0);
        half8 a1 = rd16(buf + A16_OFF, rA0 + 32, s0);
        half8 bb = rd16(buf + B16_OFF, rB,       s0);
        acc0 = MFMA16(a0, bb, acc0, 0, 0, 0);
        acc1 = MFMA16(a1, bb, acc1, 0, 0, 0);
    }
    __builtin_amdgcn_s_setprio(0);
}

__global__ __launch_bounds__(512, 1)
void screen16_kernel(const _Float16* __restrict__ q16,  // rgb16   [B][C][HW]
                     const _Float16* __restrict__ k16,  // depth16 [B][C][HW]
                     float* __restrict__ energy)        // [B][C][C]
{
    const int bid = blockIdx.x;
    const int nid = (bid & 7) * 32 + (bid >> 3);   // XCD-chunk (256%8==0: bijective)
    const int d0  = (nid & 3) * BN;
    const int c0  = ((nid >> 2) & 3) * BM;
    const int b   = nid >> 4;

    const int tid  = threadIdx.x;
    const int lane = tid & 63;
    const int w    = tid >> 6;         // 0..7
    const int wm   = w >> 2;           // 0,1: 64 rows
    const int wn   = w & 3;            // 0..3: 32 cols

    __shared__ __align__(16) char sm[2 * BUF16_SZ];

    const _Float16* qb = q16 + (size_t)b * CH * HW;
    const _Float16* kb = k16 + (size_t)b * CH * HW;

    // Per-lane DMA source offsets (f16 units). Slab i covers rows R0=16w+8i..+7;
    // lane l -> row R0+(l>>3), G-slot (l&7) ^ ((R0+(l>>3))>>1 & 7)
    //        = (l&7) ^ (4i + ((l>>3)>>1))   [8w = 0 mod 8].
    const int lr = lane >> 3, ls = lane & 7;
    const int off0 = lr * HW + ((ls ^ (     (lr >> 1))) << 3);   // i=0
    const int off1 = lr * HW + ((ls ^ (4 + (lr >> 1))) << 3);    // i=1
    const _Float16* gA0 = qb + (size_t)(c0 + 16 * w)     * HW + off0;
    const _Float16* gA1 = qb + (size_t)(c0 + 16 * w + 8) * HW + off1;
    const _Float16* gB0 = kb + (size_t)(d0 + 16 * w)     * HW + off0;
    const _Float16* gB1 = kb + (size_t)(d0 + 16 * w + 8) * HW + off1;

    // Wave-uniform LDS dest bases (DMA writes lane*16 linear = 8 rows x 128B)
    char* ldsA0o = sm + A16_OFF + (16 * w)     * 128;
    char* ldsA1o = sm + A16_OFF + (16 * w + 8) * 128;
    char* ldsB0o = sm + B16_OFF + (16 * w)     * 128;
    char* ldsB1o = sm + B16_OFF + (16 * w + 8) * 128;

    // tile t -> buffer (t&1); 4 DMA instrs per thread per tile
    #define DMA_TILE(bufsel, t) do {                    \
        const int ko_ = (t) * BK16;                     \
        const size_t bo_ = (size_t)(bufsel) * BUF16_SZ; \
        dma16(gA0 + ko_, ldsA0o + bo_);                 \
        dma16(gA1 + ko_, ldsA1o + bo_);                 \
        dma16(gB0 + ko_, ldsB0o + bo_);                 \
        dma16(gB1 + ko_, ldsB1o + bo_);                 \
    } while (0)

    // ---- prologue: tiles 0,1 in flight; tile 0 landed everywhere ----
    DMA_TILE(0, 0);
    DMA_TILE(1, 1);
    asm volatile("s_waitcnt vmcnt(4)" ::: "memory");
    __builtin_amdgcn_sched_barrier(0);
    __builtin_amdgcn_s_barrier();

    f32x16 acc0 = {}, acc1 = {};
    const int rA0 = wm * 64 + (lane & 31);
    const int rB  = wn * 32 + (lane & 31);
    const int hf  = lane >> 5;

    for (int t = 0; t < NKT16; ++t) {
        const char* rdb = sm + (size_t)(t & 1) * BUF16_SZ;
        compute16(rdb, rA0, rB, hf, acc0, acc1);
        if (t == NKT16 - 1) break;
        asm volatile("s_waitcnt lgkmcnt(0)" ::: "memory");
        __builtin_amdgcn_s_barrier();            // all waves done reading buf(t&1)
        __builtin_amdgcn_sched_barrier(0);
        if (t + 2 < NKT16) {
            DMA_TILE(t & 1, t + 2);              // refill just-freed buffer
            asm volatile("s_waitcnt vmcnt(4)" ::: "memory");   // tile t+1 landed (mine)
        } else {
            asm volatile("s_waitcnt vmcnt(0)" ::: "memory");
        }
        __builtin_amdgcn_sched_barrier(0);
        __builtin_amdgcn_s_barrier();            // tile t+1 landed (all waves)
    }
    #undef DMA_TILE

    // C-store: col = lane&31, row = (reg&3)+8*(reg>>2)+4*(lane>>5) (m74/m101)
    float* eb = energy + ((size_t)(b * CH + c0) * CH) + d0 + wn * 32 + (lane & 31);
    #pragma unroll
    for (int mi = 0; mi < 2; ++mi) {
        #pragma unroll
        for (int qr = 0; qr < 16; ++qr) {
            int rowl = wm * 64 + mi * 32 + (qr & 3) + 8 * (qr >> 2) + 4 * (lane >> 5);
            eb[(size_t)rowl * CH] = (mi == 0) ? acc0[qr] : acc1[qr];
        }
    }
}

// ===== rescore+gather (R13 verbatim): max -> candidates -> exact rescore ====
__global__ __launch_bounds__(256)
void rescore_gather_kernel(const float* __restrict__ rgb,
                           const float* __restrict__ depth,
                           const float* __restrict__ energy,
                           float* __restrict__ out)
{
    const int row = blockIdx.x;          // b*CH + c
    const int b   = row >> 9;
    const int tid = threadIdx.x;

    __shared__ float sred[4];
    __shared__ float sM;
    __shared__ int   scnt;
    __shared__ int   slist[CH];
    __shared__ unsigned long long sbest;

    const float* erow = energy + (size_t)row * CH;
    float e0 = erow[tid], e1 = erow[tid + 256];

    float m = fmaxf(e0, e1);
    #pragma unroll
    for (int off = 1; off < 64; off <<= 1) m = fmaxf(m, __shfl_xor(m, off, 64));
    if ((tid & 63) == 0) sred[tid >> 6] = m;
    __syncthreads();
    if (tid == 0) {
        sM = fmaxf(fmaxf(sred[0], sred[1]), fmaxf(sred[2], sred[3]));
        scnt = 0; sbest = 0ull;
    }
    __syncthreads();
    const float thr = sM - DELTA;
    if (e0 >= thr) { int i = atomicAdd(&scnt, 1); slist[i] = tid; }
    if (e1 >= thr) { int i = atomicAdd(&scnt, 1); slist[i] = tid + 256; }
    __syncthreads();
    const int cnt = scnt;

    const float4* q4 = (const float4*)(rgb + (size_t)row * HW);
    for (int i = 0; i < cnt; ++i) {      // uniform loop; order-independent max
        const int d = slist[i];
        const float4* k4 = (const float4*)(depth + ((size_t)(b * CH + d)) * HW);
        float s = 0.0f;
        for (int j = tid; j < HW / 4; j += 256) {
            float4 a = q4[j], bb = k4[j];
            s += a.x * bb.x + a.y * bb.y + a.z * bb.z + a.w * bb.w;
        }
        #pragma unroll
        for (int off = 1; off < 64; off <<= 1) s += __shfl_xor(s, off, 64);
        if ((tid & 63) == 0) sred[tid >> 6] = s;
        __syncthreads();
        if (tid == 0) {
            float tot = sred[0] + sred[1] + sred[2] + sred[3];
            unsigned long long p =
                ((unsigned long long)f32_sortable(tot) << 32) |
                (uint32_t)(~(uint32_t)d);        // ties -> smallest d
            if (p > sbest) sbest = p;
        }
        __syncthreads();
    }

    const int widx = (int)(~(uint32_t)(sbest & 0xFFFFFFFFull));
    const float4* w4 = (const float4*)(depth + ((size_t)(b * CH + widx)) * HW);
    float4* o4 = (float4*)(out + (size_t)row * HW);
    for (int j = tid; j < HW / 4; j += 256) {
        float4 a = q4[j], dd = w4[j];
        o4[j] = make_float4(a.x + dd.x, a.y + dd.y, a.z + dd.z, a.w + dd.w);
    }
}

// ============== FALLBACK screen (R13 verbatim, f32 reg-staged) ==============
#define BKs   64
#define NKTs  (HW / BKs)
#define AHs_OFF 0
#define BHs_OFF 16384
#define BUFs_SZ 32768

#define LGKM_BARRIER() do { \
    asm volatile("s_waitcnt lgkmcnt(0)" ::: "memory"); \
    __builtin_amdgcn_s_barrier(); \
    __builtin_amdgcn_sched_barrier(0); \
} while (0)

__device__ __forceinline__ int swzs(int r, int s) {
    return r * 128 + ((s ^ ((r >> 1) & 7)) << 4);
}

__device__ __forceinline__ half8 cvt8h(const float4& v0, const float4& v1) {
    half8 h;
    h[0] = (_Float16)v0.x; h[1] = (_Float16)v0.y;
    h[2] = (_Float16)v0.z; h[3] = (_Float16)v0.w;
    h[4] = (_Float16)v1.x; h[5] = (_Float16)v1.y;
    h[6] = (_Float16)v1.z; h[7] = (_Float16)v1.w;
    return h;
}

__device__ __forceinline__ void load_tile_s(const float* aG, const float* bG, int k0,
                                            float4 (&av)[4], float4 (&bv)[4]) {
    av[0] = *(const float4*)(aG + k0 + 0);
    av[1] = *(const float4*)(aG + k0 + 4);
    av[2] = *(const float4*)(aG + k0 + 8);
    av[3] = *(const float4*)(aG + k0 + 12);
    bv[0] = *(const float4*)(bG + k0 + 0);
    bv[1] = *(const float4*)(bG + k0 + 4);
    bv[2] = *(const float4*)(bG + k0 + 8);
    bv[3] = *(const float4*)(bG + k0 + 12);
}

__device__ __forceinline__ void stage_tile_s(char* dst,
                                             const float4 (&av)[4], const float4 (&bv)[4],
                                             int row, int q) {
    *(half8*)(dst + AHs_OFF + swzs(row, 2 * q))     = cvt8h(av[0], av[1]);
    *(half8*)(dst + AHs_OFF + swzs(row, 2 * q + 1)) = cvt8h(av[2], av[3]);
    *(half8*)(dst + BHs_OFF + swzs(row, 2 * q))     = cvt8h(bv[0], bv[1]);
    *(half8*)(dst + BHs_OFF + swzs(row, 2 * q + 1)) = cvt8h(bv[2], bv[3]);
}

__device__ __forceinline__ void compute_tile_s(const char* buf, int rA0, int rB, int half,
                                               f32x16& acc0, f32x16& acc1) {
    __builtin_amdgcn_s_setprio(1);
    #pragma unroll
    for (int kc = 0; kc < 4; ++kc) {
        const int s0 = 2 * kc + half;
        half8 ah0 = *(const half8*)(buf + AHs_OFF + swzs(rA0,      s0));
        half8 ah1 = *(const half8*)(buf + AHs_OFF + swzs(rA0 + 32, s0));
        half8 bh  = *(const half8*)(buf + BHs_OFF + swzs(rB, s0));
        acc0 = MFMA16(ah0, bh, acc0, 0, 0, 0);
        acc1 = MFMA16(ah1, bh, acc1, 0, 0, 0);
    }
    __builtin_amdgcn_s_setprio(0);
}

__global__ __launch_bounds__(512, 1)
void screen_kernel(const float* __restrict__ q,
                   const float* __restrict__ kmat,
                   float* __restrict__ energy)
{
    const int bid = blockIdx.x;
    const int nid = (bid & 7) * 32 + (bid >> 3);
    const int d0  = (nid & 3) * BN;
    const int c0  = ((nid >> 2) & 3) * BM;
    const int b   = nid >> 4;

    const int tid  = threadIdx.x;
    const int lane = tid & 63;
    const int w    = tid >> 6;
    const int wm   = w >> 2;
    const int wn   = w & 3;

    __shared__ __align__(16) char sm[2 * BUFs_SZ];
    char* buf0 = sm;
    char* buf1 = sm + BUFs_SZ;

    const float* qb = q    + (size_t)b * CH * HW;
    const float* kb = kmat + (size_t)b * CH * HW;

    const int row = tid >> 2, sq = tid & 3;
    const float* aG = qb + (size_t)(c0 + row) * HW + sq * 16;
    const float* bG = kb + (size_t)(d0 + row) * HW + sq * 16;

    float4 av0[4], bv0[4], av1[4], bv1[4];

    load_tile_s(aG, bG, 0, av0, bv0);
    stage_tile_s(buf0, av0, bv0, row, sq);
    load_tile_s(aG, bG, BKs, av1, bv1);
    LGKM_BARRIER();

    f32x16 acc0 = {}, acc1 = {};
    const int rA0  = wm * 64 + (lane & 31);
    const int rB   = wn * 32 + (lane & 31);
    const int half = lane >> 5;

    for (int kt = 0; kt < NKTs; kt += 2) {
        if (kt + 2 < NKTs) load_tile_s(aG, bG, (kt + 2) * BKs, av0, bv0);
        stage_tile_s(buf1, av1, bv1, row, sq);
        compute_tile_s(buf0, rA0, rB, half, acc0, acc1);
        LGKM_BARRIER();
        if (kt + 3 < NKTs) load_tile_s(aG, bG, (kt + 3) * BKs, av1, bv1);
        if (kt + 2 < NKTs) stage_tile_s(buf0, av0, bv0, row, sq);
        compute_tile_s(buf1, rA0, rB, half, acc0, acc1);
        LGKM_BARRIER();
    }

    float* eb = energy + ((size_t)(b * CH + c0) * CH) + d0 + wn * 32 + (lane & 31);
    #pragma unroll
    for (int mi = 0; mi < 2; ++mi) {
        #pragma unroll
        for (int qr = 0; qr < 16; ++qr) {
            int rowl = wm * 64 + mi * 32 + (qr & 3) + 8 * (qr >> 2) + 4 * (lane >> 5);
            eb[(size_t)rowl * CH] = (mi == 0) ? acc0[qr] : acc1[qr];
        }
    }
}

// ============================== LAUNCH =====================================
extern "C" void kernel_launch(void* const* d_in, const int* in_sizes, int n_in,
                              void* d_out, int out_size, void* d_ws, size_t ws_size,
                              hipStream_t stream)
{
    const float* rgb   = (const float*)d_in[0];
    const float* depth = (const float*)d_in[1];
    float* out = (float*)d_out;
    float* energy = (float*)d_ws;

    if (ws_size >= WS_FAST16) {
        _Float16* rgb16   = (_Float16*)((char*)d_ws + ENERGY_ELEMS * 4);
        _Float16* depth16 = rgb16 + N_ELEM;
        cvt_f16_kernel<<<2048, 256, 0, stream>>>(rgb, depth, rgb16, depth16);
        screen16_kernel<<<256, 512, 0, stream>>>(rgb16, depth16, energy);
        rescore_gather_kernel<<<BATCH * CH, 256, 0, stream>>>(rgb, depth, energy, out);
    } else {
        // R13 path (proven 104.4 us)
        screen_kernel<<<256, 512, 0, stream>>>(rgb, depth, energy);
        rescore_gather_kernel<<<BATCH * CH, 256, 0, stream>>>(rgb, depth, energy, out);
    }
}